// Round 12
// baseline (48.380 us; speedup 1.0000x reference)
//
#include <hip/hip_runtime.h>

// Problem constants (match reference)
#define NB 4
#define LL 2048
#define NH 12
#define DD 64
#define CB 128                 // chunk size (== reference chunk; math identical)
#define NG (LL/CB)             // 16 chunks
#define NBH (NB*NH)            // 48
#define ST_BYTES (DD*DD*2)     // 8 KB: per-chunk state bf16 [m][d] (raw, never scanned)
#define KS_BASE_BYTES ((size_t)NBH*NG*ST_BYTES)   // 6.29 MB, then raw ksum f32 region

typedef short bf16x8 __attribute__((ext_vector_type(8)));
typedef float f32x4  __attribute__((ext_vector_type(4)));

#define SWZ8(row, x)  ((x) ^ (((row) & 7) << 4))    // swizzle within 128B rows
#define SWZ16(row, x) ((x) ^ (((row) & 15) << 4))   // swizzle within 256B rows

__device__ __forceinline__ float phi(float x) {
    return x > 0.0f ? x + 1.0f : __expf(x);          // elu(x)+1
}
__device__ __forceinline__ unsigned f2bf1(float x) { // f32 -> bf16 bits (RNE)
    union { float f; unsigned u; } v; v.f = x;
    return (v.u + 0x7FFFu + ((v.u >> 16) & 1u)) >> 16;
}
__device__ __forceinline__ unsigned packbf(float a, float b) {
    return f2bf1(a) | (f2bf1(b) << 16);
}
__device__ __forceinline__ float bf2f(unsigned short u) {
    union { unsigned u; float f; } v; v.u = ((unsigned)u) << 16; return v.f;
}
__device__ __forceinline__ void addbf8(float* run, uint4 a) {
    const unsigned u[4] = {a.x, a.y, a.z, a.w};
    #pragma unroll
    for (int i = 0; i < 4; ++i) {
        run[2*i+0] += bf2f((unsigned short)(u[i] & 0xffffu));
        run[2*i+1] += bf2f((unsigned short)(u[i] >> 16));
    }
}
__device__ __forceinline__ uint4 pack8(const float* run) {
    uint4 s;
    s.x = packbf(run[0], run[1]); s.y = packbf(run[2], run[3]);
    s.z = packbf(run[4], run[5]); s.w = packbf(run[6], run[7]);
    return s;
}

// ---------------- Kernel 1: per-chunk stateT[m][d] = sum_r v[r][m]*phi(k)[r][d] (bf16)
//                  + ksum[d] = sum_r phi(k)[r][d] (f32, via ones-MFMA). RAW (no scan).
__global__ __launch_bounds__(256) void la_chunk_sums(
    const float* __restrict__ kin, const float* __restrict__ vin,
    char* __restrict__ wsb)
{
    __shared__ __align__(16) char sm[32768];  // KT [d][r] 0..16K | VT [m][r] 16..32K
    const int bid = blockIdx.x;
    const int g = bid & (NG-1);
    const int h = (bid >> 4) % NH;
    const int n = bid / (NG*NH);
    const int t = threadIdx.x;
    const int l0 = g * CB;
    const int w = t >> 6, l = t & 63, gq = l >> 4, c16 = l & 15;

    // stage phi(k), v transposed: [d][r], [m][r], 256B rows, SWZ16
    #pragma unroll
    for (int p = 0; p < 8; ++p) {
        const int i = p*256 + t;
        const int r = i >> 4, c4 = i & 15;
        const size_t gidx = ((size_t)((n*LL + l0 + r)*NH + h))*DD + c4*4;
        float4 kk = *(const float4*)(kin + gidx);
        float4 vl = *(const float4*)(vin + gidx);
        const float kf[4] = {phi(kk.x), phi(kk.y), phi(kk.z), phi(kk.w)};
        const float vf[4] = {vl.x, vl.y, vl.z, vl.w};
        #pragma unroll
        for (int j = 0; j < 4; ++j) {
            const int d = c4*4 + j;
            *(unsigned short*)(sm +         d*256 + SWZ16(d, 2*r)) = (unsigned short)f2bf1(kf[j]);
            *(unsigned short*)(sm + 16384 + d*256 + SWZ16(d, 2*r)) = (unsigned short)f2bf1(vf[j]);
        }
    }
    __syncthreads();

    const int m = 16*w + c16;
    bf16x8 va[4];
    #pragma unroll
    for (int ks = 0; ks < 4; ++ks)
        va[ks] = *(const bf16x8*)(sm + 16384 + m*256 + SWZ16(m, 64*ks + 16*gq));
    const short one = (short)0x3F80;
    const bf16x8 ones = {one, one, one, one, one, one, one, one};

    f32x4 acc[4], ksa[4];
    #pragma unroll
    for (int td = 0; td < 4; ++td) {
        acc[td] = (f32x4){0.f,0.f,0.f,0.f};
        ksa[td] = (f32x4){0.f,0.f,0.f,0.f};
    }
    #pragma unroll
    for (int td = 0; td < 4; ++td) {
        const int d = 16*td + c16;
        #pragma unroll
        for (int ks = 0; ks < 4; ++ks) {
            const bf16x8 kb = *(const bf16x8*)(sm + d*256 + SWZ16(d, 64*ks + 16*gq));
            acc[td] = __builtin_amdgcn_mfma_f32_16x16x32_bf16(va[ks], kb, acc[td], 0, 0, 0);
            ksa[td] = __builtin_amdgcn_mfma_f32_16x16x32_bf16(ones,  kb, ksa[td], 0, 0, 0);
        }
    }

    // direct global stores: raw state bf16 [m][d], linear (L2 merges 32B runs)
    char* stg = wsb + (size_t)bid * ST_BYTES;
    #pragma unroll
    for (int td = 0; td < 4; ++td)
        #pragma unroll
        for (int e = 0; e < 4; ++e) {
            const int mr = 16*w + 4*gq + e;      // C row = m
            const int d  = 16*td + c16;          // C col = d
            *(unsigned short*)(stg + mr*128 + d*2) = (unsigned short)f2bf1(acc[td][e]);
        }
    if (w == 0 && gq == 0) {   // raw ksum f32 (all C-rows equal; take e=0)
        float* ksw = (float*)(wsb + KS_BASE_BYTES) + (size_t)bid * DD;
        #pragma unroll
        for (int td = 0; td < 4; ++td)
            ksw[16*td + c16] = ksa[td][0];
    }
}

// ---------------- Kernel 2: per-chunk output via MFMA, 512 threads (8 waves).
// The exclusive scan is built IN-KERNEL: each block f32-sums its g'<g raw
// predecessor states (L3-hot, one coalesced pass) into STX. No scan dispatch.
#define SM_Q   0
#define SM_K   16384
#define SM_S   0
#define SM_VT  32768
#define SM_STX 49152
#define SM_KSX 57344
#define SM_ZL  57600
#define SM_BYTES 58112

__global__ __launch_bounds__(512) void la_output(
    const float* __restrict__ qin, const float* __restrict__ kin,
    const float* __restrict__ vin, const char* __restrict__ wsb,
    float* __restrict__ out)
{
    __shared__ __align__(16) char sm[SM_BYTES];
    const int bid = blockIdx.x;
    const int g = bid & (NG-1);
    const int h = (bid >> 4) % NH;
    const int n = bid / (NG*NH);
    const int nh = n*NH + h;
    const int t = threadIdx.x;
    const int l0 = g * CB;
    const int w = t >> 6, l = t & 63, gq = l >> 4, c16 = l & 15;
    const int c = 16*w + c16;            // this lane's column (query row) 0..127

    // ---- stage phi(q),phi(k) row-major (SWZ8); v transposed (SWZ16) ----
    #pragma unroll
    for (int p = 0; p < 4; ++p) {
        const int i = p*512 + t;
        const int r = i >> 4, c4 = i & 15;
        const size_t gidx = ((size_t)((n*LL + l0 + r)*NH + h))*DD + c4*4;
        float4 qq = *(const float4*)(qin + gidx);
        float4 kk = *(const float4*)(kin + gidx);
        float4 vl = *(const float4*)(vin + gidx);
        uint2 qp; qp.x = packbf(phi(qq.x), phi(qq.y)); qp.y = packbf(phi(qq.z), phi(qq.w));
        uint2 kp; kp.x = packbf(phi(kk.x), phi(kk.y)); kp.y = packbf(phi(kk.z), phi(kk.w));
        *(uint2*)(sm + SM_Q + r*128 + SWZ8(r, c4*8)) = qp;
        *(uint2*)(sm + SM_K + r*128 + SWZ8(r, c4*8)) = kp;
        const float vf[4] = {vl.x, vl.y, vl.z, vl.w};
        #pragma unroll
        for (int j = 0; j < 4; ++j) {
            const int m = c4*4 + j;
            *(unsigned short*)(sm + SM_VT + m*256 + SWZ16(m, 2*r)) = (unsigned short)f2bf1(vf[j]);
        }
    }
    // ---- in-kernel exclusive scan: STX = sum of raw states g'<g (f32 acc) ----
    // 512 threads x 1 uint4 slot; per step a fully-coalesced 8KB block read (L3-hot).
    {
        const int mr = t >> 3, cc = t & 7;
        float run[8];
        #pragma unroll
        for (int i = 0; i < 8; ++i) run[i] = 0.f;
        const char* stb = wsb + (size_t)nh * NG * ST_BYTES + mr*128 + cc*16;
        for (int gg = 0; gg < g; ++gg)
            addbf8(run, *(const uint4*)(stb + (size_t)gg * ST_BYTES));
        *(uint4*)(sm + SM_STX + mr*128 + SWZ8(mr, cc*16)) = pack8(run);
    }
    // ---- ksum_excl: f32 sum of raw per-chunk ksums g'<g ----
    if (t < DD) {
        const float* ksb = (const float*)(wsb + KS_BASE_BYTES) + (size_t)nh * NG * DD + t;
        float run = 0.f;
        for (int gg = 0; gg < g; ++gg) run += ksb[(size_t)gg * DD];
        ((float*)(sm + SM_KSX))[t] = run;
    }
    __syncthreads();

    // ---- q fragments (kept in regs through both phases) ----
    const bf16x8 qf0 = *(const bf16x8*)(sm + SM_Q + c*128 + SWZ8(c, 16*gq));
    const bf16x8 qf1 = *(const bf16x8*)(sm + SM_Q + c*128 + SWZ8(c, 64 + 16*gq));

    // ---- scores: S^T tiles, 8 r-tiles of 16 ----
    f32x4 sreg[8];
    #pragma unroll
    for (int tr = 0; tr < 8; ++tr) {
        const int r = 16*tr + c16;
        const bf16x8 ka0 = *(const bf16x8*)(sm + SM_K + r*128 + SWZ8(r, 16*gq));
        const bf16x8 ka1 = *(const bf16x8*)(sm + SM_K + r*128 + SWZ8(r, 64 + 16*gq));
        f32x4 a; a[0]=0.f; a[1]=0.f; a[2]=0.f; a[3]=0.f;
        a = __builtin_amdgcn_mfma_f32_16x16x32_bf16(ka0, qf0, a, 0, 0, 0);
        a = __builtin_amdgcn_mfma_f32_16x16x32_bf16(ka1, qf1, a, 0, 0, 0);
        sreg[tr] = a;
    }
    // causal mask (keep r <= c) + z intra partial
    float z = 0.f;
    #pragma unroll
    for (int tr = 0; tr < 8; ++tr)
        #pragma unroll
        for (int e = 0; e < 4; ++e) {
            const int rr = 16*tr + 4*gq + e;
            if (rr <= c) z += sreg[tr][e]; else sreg[tr][e] = 0.f;
        }
    // z inter partial from qf regs (lane holds d=8gq+[0,8) and 32+8gq+[0,8))
    {
        const float* ksxf = (const float*)(sm + SM_KSX);
        #pragma unroll
        for (int i = 0; i < 8; ++i) {
            z += bf2f((unsigned short)qf0[i]) * ksxf[8*gq + i];
            z += bf2f((unsigned short)qf1[i]) * ksxf[32 + 8*gq + i];
        }
    }
    z += __shfl_xor(z, 16);
    z += __shfl_xor(z, 32);
    __syncthreads();   // all Q/K LDS reads done before S overlays them

    // ---- write masked S bf16 as S[c][r] (256B rows, SWZ16) ----
    #pragma unroll
    for (int tr = 0; tr < 8; ++tr) {
        uint2 sp; sp.x = packbf(sreg[tr][0], sreg[tr][1]); sp.y = packbf(sreg[tr][2], sreg[tr][3]);
        *(uint2*)(sm + SM_S + c*256 + SWZ16(c, 32*tr + 8*gq)) = sp;
    }
    if (gq == 0) ((float*)(sm + SM_ZL))[c] = z;
    __syncthreads();

    // ---- PV intra (k=r, 4 steps) + inter (k=d, 2 steps) ----
    bf16x8 sf[4];
    #pragma unroll
    for (int ks = 0; ks < 4; ++ks)
        sf[ks] = *(const bf16x8*)(sm + SM_S + c*256 + SWZ16(c, 64*ks + 16*gq));
    f32x4 acc[4];
    #pragma unroll
    for (int tm = 0; tm < 4; ++tm) { acc[tm][0]=0.f; acc[tm][1]=0.f; acc[tm][2]=0.f; acc[tm][3]=0.f; }
    #pragma unroll
    for (int tm = 0; tm < 4; ++tm) {
        const int m = 16*tm + c16;
        #pragma unroll
        for (int ks = 0; ks < 4; ++ks) {
            const bf16x8 vf = *(const bf16x8*)(sm + SM_VT + m*256 + SWZ16(m, 64*ks + 16*gq));
            acc[tm] = __builtin_amdgcn_mfma_f32_16x16x32_bf16(sf[ks], vf, acc[tm], 0, 0, 0);
        }
        const bf16x8 st0 = *(const bf16x8*)(sm + SM_STX + m*128 + SWZ8(m, 16*gq));
        const bf16x8 st1 = *(const bf16x8*)(sm + SM_STX + m*128 + SWZ8(m, 64 + 16*gq));
        acc[tm] = __builtin_amdgcn_mfma_f32_16x16x32_bf16(qf0, st0, acc[tm], 0, 0, 0);
        acc[tm] = __builtin_amdgcn_mfma_f32_16x16x32_bf16(qf1, st1, acc[tm], 0, 0, 0);
    }

    // ---- epilogue ----
    float zinv[4];
    #pragma unroll
    for (int e = 0; e < 4; ++e) {
        const float zr = ((const float*)(sm + SM_ZL))[16*w + 4*gq + e];
        zinv[e] = 1.0f / (zr + 1e-6f);
    }
    #pragma unroll
    for (int tm = 0; tm < 4; ++tm)
        #pragma unroll
        for (int e = 0; e < 4; ++e) {
            const int cr = 16*w + 4*gq + e;
            const int m  = 16*tm + c16;
            out[((size_t)((n*LL + l0 + cr)*NH + h))*DD + m] = acc[tm][e] * zinv[e];
        }
}

extern "C" void kernel_launch(void* const* d_in, const int* in_sizes, int n_in,
                              void* d_out, int out_size, void* d_ws, size_t ws_size,
                              hipStream_t stream) {
    const float* q = (const float*)d_in[0];
    const float* k = (const float*)d_in[1];
    const float* v = (const float*)d_in[2];
    float* out = (float*)d_out;
    char* wsb  = (char*)d_ws;   // raw chunk states bf16 6.29 MB + raw ksums f32 0.2 MB

    const int nblk = NB * NH * NG;   // 768
    la_chunk_sums<<<nblk, 256, 0, stream>>>(k, v, wsb);
    la_output<<<nblk, 512, 0, stream>>>(q, k, v, wsb, out);
}

// Round 13
// 46.677 us; speedup vs baseline: 1.0365x; 1.0365x over previous
//
#include <hip/hip_runtime.h>

// Problem constants (match reference)
#define NB 4
#define LL 2048
#define NH 12
#define DD 64
#define CB 128                 // chunk size (== reference chunk; math identical)
#define NG (LL/CB)             // 16 chunks
#define NBH (NB*NH)            // 48
#define ST_BYTES (DD*DD*2)     // 8 KB: per-chunk state bf16 [m][d]
#define KS_BASE_BYTES ((size_t)NBH*NG*ST_BYTES)   // 6.29 MB, then ksum f32 region

typedef short bf16x8 __attribute__((ext_vector_type(8)));
typedef float f32x4  __attribute__((ext_vector_type(4)));

#define SWZ8(row, x)  ((x) ^ (((row) & 7) << 4))    // swizzle within 128B rows
#define SWZ16(row, x) ((x) ^ (((row) & 15) << 4))   // swizzle within 256B rows

__device__ __forceinline__ float phi(float x) {
    return x > 0.0f ? x + 1.0f : __expf(x);          // elu(x)+1
}
__device__ __forceinline__ unsigned f2bf1(float x) { // f32 -> bf16 bits (RNE)
    union { float f; unsigned u; } v; v.f = x;
    return (v.u + 0x7FFFu + ((v.u >> 16) & 1u)) >> 16;
}
__device__ __forceinline__ unsigned packbf(float a, float b) {
    return f2bf1(a) | (f2bf1(b) << 16);
}
__device__ __forceinline__ float bf2f(unsigned short u) {
    union { unsigned u; float f; } v; v.u = ((unsigned)u) << 16; return v.f;
}
__device__ __forceinline__ void addbf8(float* run, uint4 a) {
    const unsigned u[4] = {a.x, a.y, a.z, a.w};
    #pragma unroll
    for (int i = 0; i < 4; ++i) {
        run[2*i+0] += bf2f((unsigned short)(u[i] & 0xffffu));
        run[2*i+1] += bf2f((unsigned short)(u[i] >> 16));
    }
}
__device__ __forceinline__ uint4 pack8(const float* run) {
    uint4 s;
    s.x = packbf(run[0], run[1]); s.y = packbf(run[2], run[3]);
    s.z = packbf(run[4], run[5]); s.w = packbf(run[6], run[7]);
    return s;
}

// ---------------- Kernel 1: per-chunk stateT[m][d] = sum_r v[r][m]*phi(k)[r][d] (bf16)
//                  + ksum[d] = sum_r phi(k)[r][d] (f32, via ones-MFMA)
__global__ __launch_bounds__(256) void la_chunk_sums(
    const float* __restrict__ kin, const float* __restrict__ vin,
    char* __restrict__ wsb)
{
    __shared__ __align__(16) char sm[32768];  // KT [d][r] 0..16K | VT [m][r] 16..32K
    const int bid = blockIdx.x;
    const int g = bid & (NG-1);
    const int h = (bid >> 4) % NH;
    const int n = bid / (NG*NH);
    const int t = threadIdx.x;
    const int l0 = g * CB;
    const int w = t >> 6, l = t & 63, gq = l >> 4, c16 = l & 15;

    // stage phi(k), v transposed: [d][r], [m][r], 256B rows, SWZ16
    #pragma unroll
    for (int p = 0; p < 8; ++p) {
        const int i = p*256 + t;
        const int r = i >> 4, c4 = i & 15;
        const size_t gidx = ((size_t)((n*LL + l0 + r)*NH + h))*DD + c4*4;
        float4 kk = *(const float4*)(kin + gidx);
        float4 vl = *(const float4*)(vin + gidx);
        const float kf[4] = {phi(kk.x), phi(kk.y), phi(kk.z), phi(kk.w)};
        const float vf[4] = {vl.x, vl.y, vl.z, vl.w};
        #pragma unroll
        for (int j = 0; j < 4; ++j) {
            const int d = c4*4 + j;
            *(unsigned short*)(sm +         d*256 + SWZ16(d, 2*r)) = (unsigned short)f2bf1(kf[j]);
            *(unsigned short*)(sm + 16384 + d*256 + SWZ16(d, 2*r)) = (unsigned short)f2bf1(vf[j]);
        }
    }
    __syncthreads();

    const int m = 16*w + c16;
    bf16x8 va[4];
    #pragma unroll
    for (int ks = 0; ks < 4; ++ks)
        va[ks] = *(const bf16x8*)(sm + 16384 + m*256 + SWZ16(m, 64*ks + 16*gq));
    const short one = (short)0x3F80;
    const bf16x8 ones = {one, one, one, one, one, one, one, one};

    f32x4 acc[4], ksa[4];
    #pragma unroll
    for (int td = 0; td < 4; ++td) {
        acc[td] = (f32x4){0.f,0.f,0.f,0.f};
        ksa[td] = (f32x4){0.f,0.f,0.f,0.f};
    }
    #pragma unroll
    for (int td = 0; td < 4; ++td) {
        const int d = 16*td + c16;
        #pragma unroll
        for (int ks = 0; ks < 4; ++ks) {
            const bf16x8 kb = *(const bf16x8*)(sm + d*256 + SWZ16(d, 64*ks + 16*gq));
            acc[td] = __builtin_amdgcn_mfma_f32_16x16x32_bf16(va[ks], kb, acc[td], 0, 0, 0);
            ksa[td] = __builtin_amdgcn_mfma_f32_16x16x32_bf16(ones,  kb, ksa[td], 0, 0, 0);
        }
    }

    // direct global stores: raw state bf16 [m][d], linear (L2 merges 32B runs)
    char* stg = wsb + (size_t)bid * ST_BYTES;
    #pragma unroll
    for (int td = 0; td < 4; ++td)
        #pragma unroll
        for (int e = 0; e < 4; ++e) {
            const int mr = 16*w + 4*gq + e;      // C row = m
            const int d  = 16*td + c16;          // C col = d
            *(unsigned short*)(stg + mr*128 + d*2) = (unsigned short)f2bf1(acc[td][e]);
        }
    if (w == 0 && gq == 0) {   // ksum f32 (all C-rows equal; take e=0)
        float* ksw = (float*)(wsb + KS_BASE_BYTES) + (size_t)bid * DD;
        #pragma unroll
        for (int td = 0; td < 4; ++td)
            ksw[16*td + c16] = ksa[td][0];
    }
}

// ---------------- Kernel 2: exclusive prefix scan over chunks (per n,h), in place
__global__ __launch_bounds__(256) void la_scan(char* __restrict__ wsb)
{
    const int nh = blockIdx.x / 3;
    const int sl = blockIdx.x % 3;
    const int t  = threadIdx.x;
    if (sl < 2) {
        const int t4 = sl*256 + t;                 // 0..511 uint4 slots of 8KB chunk
        char* base = wsb + (size_t)nh * NG * ST_BYTES + (size_t)t4 * 16;
        float run[8];
        #pragma unroll
        for (int i = 0; i < 8; ++i) run[i] = 0.f;
        #pragma unroll
        for (int g2 = 0; g2 < NG; g2 += 2) {
            uint4 a0 = *(uint4*)(base + (size_t)(g2+0)*ST_BYTES);
            uint4 a1 = *(uint4*)(base + (size_t)(g2+1)*ST_BYTES);
            *(uint4*)(base + (size_t)(g2+0)*ST_BYTES) = pack8(run);
            addbf8(run, a0);
            *(uint4*)(base + (size_t)(g2+1)*ST_BYTES) = pack8(run);
            addbf8(run, a1);
        }
    } else if (t < DD) {
        float* base = (float*)(wsb + KS_BASE_BYTES) + (size_t)nh * NG * DD + t;
        float run = 0.f;
        #pragma unroll
        for (int g4 = 0; g4 < NG; g4 += 4) {
            float a0 = base[(g4+0)*DD], a1 = base[(g4+1)*DD];
            float a2 = base[(g4+2)*DD], a3 = base[(g4+3)*DD];
            base[(g4+0)*DD] = run; run += a0;
            base[(g4+1)*DD] = run; run += a1;
            base[(g4+2)*DD] = run; run += a2;
            base[(g4+3)*DD] = run; run += a3;
        }
    }
}

// ---------------- Kernel 3: round-10 structure, LDS cut to 49.4 KB -> 3 blocks/CU.
// STX dropped (state fragments = per-lane 16B global loads, L2-hot, issued under
// the S-write barrier); ZL dropped (z transpose via width-16 shfl).
// LDS: Q[c][d] 0..16K (S[c][r] overlays after scores), K[r][d] 16..32K,
//      VT[m][r] 32..48K, KSX f32[64].
#define SM_Q   0
#define SM_K   16384
#define SM_S   0
#define SM_VT  32768
#define SM_KSX 49152
#define SM_BYTES 49408

__global__ __launch_bounds__(512, 6) void la_output(
    const float* __restrict__ qin, const float* __restrict__ kin,
    const float* __restrict__ vin, const char* __restrict__ wsb,
    float* __restrict__ out)
{
    __shared__ __align__(16) char sm[SM_BYTES];
    const int bid = blockIdx.x;
    const int g = bid & (NG-1);
    const int h = (bid >> 4) % NH;
    const int n = bid / (NG*NH);
    const int t = threadIdx.x;
    const int l0 = g * CB;
    const int w = t >> 6, l = t & 63, gq = l >> 4, c16 = l & 15;
    const int c = 16*w + c16;            // this lane's column (query row) 0..127

    // ---- stage phi(q),phi(k) row-major (SWZ8); v transposed (SWZ16) ----
    #pragma unroll
    for (int p = 0; p < 4; ++p) {
        const int i = p*512 + t;
        const int r = i >> 4, c4 = i & 15;
        const size_t gidx = ((size_t)((n*LL + l0 + r)*NH + h))*DD + c4*4;
        float4 qq = *(const float4*)(qin + gidx);
        float4 kk = *(const float4*)(kin + gidx);
        float4 vl = *(const float4*)(vin + gidx);
        uint2 qp; qp.x = packbf(phi(qq.x), phi(qq.y)); qp.y = packbf(phi(qq.z), phi(qq.w));
        uint2 kp; kp.x = packbf(phi(kk.x), phi(kk.y)); kp.y = packbf(phi(kk.z), phi(kk.w));
        *(uint2*)(sm + SM_Q + r*128 + SWZ8(r, c4*8)) = qp;
        *(uint2*)(sm + SM_K + r*128 + SWZ8(r, c4*8)) = kp;
        const float vf[4] = {vl.x, vl.y, vl.z, vl.w};
        #pragma unroll
        for (int j = 0; j < 4; ++j) {
            const int m = c4*4 + j;
            *(unsigned short*)(sm + SM_VT + m*256 + SWZ16(m, 2*r)) = (unsigned short)f2bf1(vf[j]);
        }
    }
    if (t < DD)
        ((float*)(sm + SM_KSX))[t] =
            ((const float*)(wsb + KS_BASE_BYTES))[(size_t)bid * DD + t];
    __syncthreads();

    // ---- q fragments (kept in regs through both phases) ----
    const bf16x8 qf0 = *(const bf16x8*)(sm + SM_Q + c*128 + SWZ8(c, 16*gq));
    const bf16x8 qf1 = *(const bf16x8*)(sm + SM_Q + c*128 + SWZ8(c, 64 + 16*gq));

    // ---- scores: S^T tiles, 8 r-tiles of 16 ----
    f32x4 sreg[8];
    #pragma unroll
    for (int tr = 0; tr < 8; ++tr) {
        const int r = 16*tr + c16;
        const bf16x8 ka0 = *(const bf16x8*)(sm + SM_K + r*128 + SWZ8(r, 16*gq));
        const bf16x8 ka1 = *(const bf16x8*)(sm + SM_K + r*128 + SWZ8(r, 64 + 16*gq));
        f32x4 a; a[0]=0.f; a[1]=0.f; a[2]=0.f; a[3]=0.f;
        a = __builtin_amdgcn_mfma_f32_16x16x32_bf16(ka0, qf0, a, 0, 0, 0);
        a = __builtin_amdgcn_mfma_f32_16x16x32_bf16(ka1, qf1, a, 0, 0, 0);
        sreg[tr] = a;
    }
    // causal mask (keep r <= c) + z intra partial
    float z = 0.f;
    #pragma unroll
    for (int tr = 0; tr < 8; ++tr)
        #pragma unroll
        for (int e = 0; e < 4; ++e) {
            const int rr = 16*tr + 4*gq + e;
            if (rr <= c) z += sreg[tr][e]; else sreg[tr][e] = 0.f;
        }
    // z inter partial from qf regs (lane holds d=8gq+[0,8) and 32+8gq+[0,8))
    {
        const float* ksxf = (const float*)(sm + SM_KSX);
        #pragma unroll
        for (int i = 0; i < 8; ++i) {
            z += bf2f((unsigned short)qf0[i]) * ksxf[8*gq + i];
            z += bf2f((unsigned short)qf1[i]) * ksxf[32 + 8*gq + i];
        }
    }
    z += __shfl_xor(z, 16);
    z += __shfl_xor(z, 32);          // z uniform over gq; indexed by c16
    __syncthreads();   // all Q/K LDS reads done before S overlays them

    // ---- scanned-state fragments: per-lane 16B global loads (L2-hot), issued
    // here so they're in flight under the S-write + barrier ----
    const char* stg = wsb + (size_t)bid * ST_BYTES;
    bf16x8 stf[4][2];
    #pragma unroll
    for (int tm = 0; tm < 4; ++tm) {
        const int m = 16*tm + c16;
        stf[tm][0] = *(const bf16x8*)(stg + m*128 +      16*gq);
        stf[tm][1] = *(const bf16x8*)(stg + m*128 + 64 + 16*gq);
    }

    // ---- write masked S bf16 as S[c][r] (256B rows, SWZ16) ----
    #pragma unroll
    for (int tr = 0; tr < 8; ++tr) {
        uint2 sp; sp.x = packbf(sreg[tr][0], sreg[tr][1]); sp.y = packbf(sreg[tr][2], sreg[tr][3]);
        *(uint2*)(sm + SM_S + c*256 + SWZ16(c, 32*tr + 8*gq)) = sp;
    }
    __syncthreads();

    // ---- PV intra (k=r, 4 steps) + inter (k=d, 2 steps) ----
    bf16x8 sf[4];
    #pragma unroll
    for (int ks = 0; ks < 4; ++ks)
        sf[ks] = *(const bf16x8*)(sm + SM_S + c*256 + SWZ16(c, 64*ks + 16*gq));
    f32x4 acc[4];
    #pragma unroll
    for (int tm = 0; tm < 4; ++tm) { acc[tm][0]=0.f; acc[tm][1]=0.f; acc[tm][2]=0.f; acc[tm][3]=0.f; }
    #pragma unroll
    for (int tm = 0; tm < 4; ++tm) {
        const int m = 16*tm + c16;
        #pragma unroll
        for (int ks = 0; ks < 4; ++ks) {
            const bf16x8 vf = *(const bf16x8*)(sm + SM_VT + m*256 + SWZ16(m, 64*ks + 16*gq));
            acc[tm] = __builtin_amdgcn_mfma_f32_16x16x32_bf16(sf[ks], vf, acc[tm], 0, 0, 0);
        }
        acc[tm] = __builtin_amdgcn_mfma_f32_16x16x32_bf16(qf0, stf[tm][0], acc[tm], 0, 0, 0);
        acc[tm] = __builtin_amdgcn_mfma_f32_16x16x32_bf16(qf1, stf[tm][1], acc[tm], 0, 0, 0);
    }

    // ---- z transpose via width-16 shfl (z of column 16w + 4gq + e) ----
    float zinv[4];
    #pragma unroll
    for (int e = 0; e < 4; ++e) {
        const float zr = __shfl(z, 4*gq + e, 16);
        zinv[e] = 1.0f / (zr + 1e-6f);
    }

    // ---- epilogue ----
    #pragma unroll
    for (int tm = 0; tm < 4; ++tm)
        #pragma unroll
        for (int e = 0; e < 4; ++e) {
            const int cr = 16*w + 4*gq + e;
            const int m  = 16*tm + c16;
            out[((size_t)((n*LL + l0 + cr)*NH + h))*DD + m] = acc[tm][e] * zinv[e];
        }
}

extern "C" void kernel_launch(void* const* d_in, const int* in_sizes, int n_in,
                              void* d_out, int out_size, void* d_ws, size_t ws_size,
                              hipStream_t stream) {
    const float* q = (const float*)d_in[0];
    const float* k = (const float*)d_in[1];
    const float* v = (const float*)d_in[2];
    float* out = (float*)d_out;
    char* wsb  = (char*)d_ws;   // state bf16 6.29 MB + ksum f32 0.2 MB

    const int nblk = NB * NH * NG;   // 768
    la_chunk_sums<<<nblk, 256, 0, stream>>>(k, v, wsb);
    la_scan<<<NBH*3, 256, 0, stream>>>(wsb);
    la_output<<<nblk, 512, 0, stream>>>(q, k, v, wsb, out);
}

// Round 14
// 40.620 us; speedup vs baseline: 1.1911x; 1.1491x over previous
//
#include <hip/hip_runtime.h>

// Problem constants (match reference)
#define NB 4
#define LL 2048
#define NH 12
#define DD 64
#define CB 128                 // chunk size (== reference chunk; math identical)
#define NG (LL/CB)             // 16 chunks
#define NBH (NB*NH)            // 48
#define ST_BYTES (DD*DD*2)     // 8 KB: per-chunk state bf16 [m][d]
#define KS_BASE_BYTES ((size_t)NBH*NG*ST_BYTES)   // 6.29 MB, then ksum f32 region

typedef short bf16x8 __attribute__((ext_vector_type(8)));
typedef float f32x4  __attribute__((ext_vector_type(4)));

#define SWZ8(row, x)  ((x) ^ (((row) & 7) << 4))    // swizzle within 128B rows
#define SWZ16(row, x) ((x) ^ (((row) & 15) << 4))   // swizzle within 256B rows

__device__ __forceinline__ float phi(float x) {
    return x > 0.0f ? x + 1.0f : __expf(x);          // elu(x)+1
}
__device__ __forceinline__ unsigned f2bf1(float x) { // f32 -> bf16 bits (RNE)
    union { float f; unsigned u; } v; v.f = x;
    return (v.u + 0x7FFFu + ((v.u >> 16) & 1u)) >> 16;
}
__device__ __forceinline__ unsigned packbf(float a, float b) {
    return f2bf1(a) | (f2bf1(b) << 16);
}
__device__ __forceinline__ float bf2f(unsigned short u) {
    union { unsigned u; float f; } v; v.u = ((unsigned)u) << 16; return v.f;
}
__device__ __forceinline__ void addbf8(float* run, uint4 a) {
    const unsigned u[4] = {a.x, a.y, a.z, a.w};
    #pragma unroll
    for (int i = 0; i < 4; ++i) {
        run[2*i+0] += bf2f((unsigned short)(u[i] & 0xffffu));
        run[2*i+1] += bf2f((unsigned short)(u[i] >> 16));
    }
}
__device__ __forceinline__ uint4 pack8(const float* run) {
    uint4 s;
    s.x = packbf(run[0], run[1]); s.y = packbf(run[2], run[3]);
    s.z = packbf(run[4], run[5]); s.w = packbf(run[6], run[7]);
    return s;
}

// ---------------- Kernel 1: per-chunk stateT[m][d] = sum_r v[r][m]*phi(k)[r][d] (bf16)
//                  + ksum[d] = sum_r phi(k)[r][d] (f32, via ones-MFMA)
// State written DIRECTLY from acc regs (32B runs coalesce in write-through L2).
__global__ __launch_bounds__(256) void la_chunk_sums(
    const float* __restrict__ kin, const float* __restrict__ vin,
    char* __restrict__ wsb)
{
    __shared__ __align__(16) char sm[32768];  // KT [d][r] 0..16K | VT [m][r] 16..32K
    const int bid = blockIdx.x;
    const int g = bid & (NG-1);
    const int h = (bid >> 4) % NH;
    const int n = bid / (NG*NH);
    const int t = threadIdx.x;
    const int l0 = g * CB;
    const int w = t >> 6, l = t & 63, gq = l >> 4, c16 = l & 15;

    // stage phi(k), v transposed: [d][r], [m][r], 256B rows, SWZ16
    #pragma unroll
    for (int p = 0; p < 8; ++p) {
        const int i = p*256 + t;
        const int r = i >> 4, c4 = i & 15;
        const size_t gidx = ((size_t)((n*LL + l0 + r)*NH + h))*DD + c4*4;
        float4 kk = *(const float4*)(kin + gidx);
        float4 vl = *(const float4*)(vin + gidx);
        const float kf[4] = {phi(kk.x), phi(kk.y), phi(kk.z), phi(kk.w)};
        const float vf[4] = {vl.x, vl.y, vl.z, vl.w};
        #pragma unroll
        for (int j = 0; j < 4; ++j) {
            const int d = c4*4 + j;
            *(unsigned short*)(sm +         d*256 + SWZ16(d, 2*r)) = (unsigned short)f2bf1(kf[j]);
            *(unsigned short*)(sm + 16384 + d*256 + SWZ16(d, 2*r)) = (unsigned short)f2bf1(vf[j]);
        }
    }
    __syncthreads();

    const int m = 16*w + c16;
    bf16x8 va[4];
    #pragma unroll
    for (int ks = 0; ks < 4; ++ks)
        va[ks] = *(const bf16x8*)(sm + 16384 + m*256 + SWZ16(m, 64*ks + 16*gq));
    const short one = (short)0x3F80;
    const bf16x8 ones = {one, one, one, one, one, one, one, one};

    f32x4 acc[4], ksa[4];
    #pragma unroll
    for (int td = 0; td < 4; ++td) {
        acc[td] = (f32x4){0.f,0.f,0.f,0.f};
        ksa[td] = (f32x4){0.f,0.f,0.f,0.f};
    }
    #pragma unroll
    for (int td = 0; td < 4; ++td) {
        const int d = 16*td + c16;
        #pragma unroll
        for (int ks = 0; ks < 4; ++ks) {
            const bf16x8 kb = *(const bf16x8*)(sm + d*256 + SWZ16(d, 64*ks + 16*gq));
            acc[td] = __builtin_amdgcn_mfma_f32_16x16x32_bf16(va[ks], kb, acc[td], 0, 0, 0);
            ksa[td] = __builtin_amdgcn_mfma_f32_16x16x32_bf16(ones,  kb, ksa[td], 0, 0, 0);
        }
    }

    // direct global stores: state bf16 [m][d], linear layout (L2 merges 32B runs)
    char* stg = wsb + (size_t)bid * ST_BYTES;
    #pragma unroll
    for (int td = 0; td < 4; ++td)
        #pragma unroll
        for (int e = 0; e < 4; ++e) {
            const int mr = 16*w + 4*gq + e;      // C row = m
            const int d  = 16*td + c16;          // C col = d
            *(unsigned short*)(stg + mr*128 + d*2) = (unsigned short)f2bf1(acc[td][e]);
        }
    if (w == 0 && gq == 0) {   // ksum f32 (all C-rows equal; take e=0)
        float* ksw = (float*)(wsb + KS_BASE_BYTES) + (size_t)bid * DD;
        #pragma unroll
        for (int td = 0; td < 4; ++td)
            ksw[16*td + c16] = ksa[td][0];
    }
}

// ---------------- Kernel 2: exclusive prefix scan over chunks (per n,h), in place
// slices 0,1: state bf16 (f32 running sum in regs); slice 2: ksum f32
__global__ __launch_bounds__(256) void la_scan(char* __restrict__ wsb)
{
    const int nh = blockIdx.x / 3;
    const int sl = blockIdx.x % 3;
    const int t  = threadIdx.x;
    if (sl < 2) {
        const int t4 = sl*256 + t;                 // 0..511 uint4 slots of 8KB chunk
        char* base = wsb + (size_t)nh * NG * ST_BYTES + (size_t)t4 * 16;
        float run[8];
        #pragma unroll
        for (int i = 0; i < 8; ++i) run[i] = 0.f;
        #pragma unroll
        for (int g2 = 0; g2 < NG; g2 += 2) {
            uint4 a0 = *(uint4*)(base + (size_t)(g2+0)*ST_BYTES);
            uint4 a1 = *(uint4*)(base + (size_t)(g2+1)*ST_BYTES);
            *(uint4*)(base + (size_t)(g2+0)*ST_BYTES) = pack8(run);
            addbf8(run, a0);
            *(uint4*)(base + (size_t)(g2+1)*ST_BYTES) = pack8(run);
            addbf8(run, a1);
        }
    } else if (t < DD) {
        float* base = (float*)(wsb + KS_BASE_BYTES) + (size_t)nh * NG * DD + t;
        float run = 0.f;
        #pragma unroll
        for (int g4 = 0; g4 < NG; g4 += 4) {
            float a0 = base[(g4+0)*DD], a1 = base[(g4+1)*DD];
            float a2 = base[(g4+2)*DD], a3 = base[(g4+3)*DD];
            base[(g4+0)*DD] = run; run += a0;
            base[(g4+1)*DD] = run; run += a1;
            base[(g4+2)*DD] = run; run += a2;
            base[(g4+3)*DD] = run; run += a3;
        }
    }
}

// ---------------- Kernel 3: per-chunk output via MFMA, 512 threads (8 waves)
// (measured-best round-4/10 version)
// LDS: Q[c][d] 0..16K, K[r][d] 16..32K (S[c][r] overlays 0..32K after scores),
//      VT[m][r] 32..48K, STX[m][d] 48..56K, KSX f32[64], ZL f32[128]
#define SM_Q   0
#define SM_K   16384
#define SM_S   0
#define SM_VT  32768
#define SM_STX 49152
#define SM_KSX 57344
#define SM_ZL  57600
#define SM_BYTES 58112

__global__ __launch_bounds__(512) void la_output(
    const float* __restrict__ qin, const float* __restrict__ kin,
    const float* __restrict__ vin, const char* __restrict__ wsb,
    float* __restrict__ out)
{
    __shared__ __align__(16) char sm[SM_BYTES];
    const int bid = blockIdx.x;
    const int g = bid & (NG-1);
    const int h = (bid >> 4) % NH;
    const int n = bid / (NG*NH);
    const int t = threadIdx.x;
    const int l0 = g * CB;
    const int w = t >> 6, l = t & 63, gq = l >> 4, c16 = l & 15;
    const int c = 16*w + c16;            // this lane's column (query row) 0..127

    // ---- stage phi(q),phi(k) row-major (SWZ8); v transposed (SWZ16) ----
    #pragma unroll
    for (int p = 0; p < 4; ++p) {
        const int i = p*512 + t;
        const int r = i >> 4, c4 = i & 15;
        const size_t gidx = ((size_t)((n*LL + l0 + r)*NH + h))*DD + c4*4;
        float4 qq = *(const float4*)(qin + gidx);
        float4 kk = *(const float4*)(kin + gidx);
        float4 vl = *(const float4*)(vin + gidx);
        uint2 qp; qp.x = packbf(phi(qq.x), phi(qq.y)); qp.y = packbf(phi(qq.z), phi(qq.w));
        uint2 kp; kp.x = packbf(phi(kk.x), phi(kk.y)); kp.y = packbf(phi(kk.z), phi(kk.w));
        *(uint2*)(sm + SM_Q + r*128 + SWZ8(r, c4*8)) = qp;
        *(uint2*)(sm + SM_K + r*128 + SWZ8(r, c4*8)) = kp;
        const float vf[4] = {vl.x, vl.y, vl.z, vl.w};
        #pragma unroll
        for (int j = 0; j < 4; ++j) {
            const int m = c4*4 + j;
            *(unsigned short*)(sm + SM_VT + m*256 + SWZ16(m, 2*r)) = (unsigned short)f2bf1(vf[j]);
        }
    }
    // state bf16 (already exclusive-scanned): linear -> STX swizzled
    {
        const char* stg = wsb + (size_t)bid * ST_BYTES;
        const int mr = t >> 3, cc = t & 7;
        *(uint4*)(sm + SM_STX + mr*128 + SWZ8(mr, cc*16)) = *(const uint4*)(stg + mr*128 + cc*16);
    }
    if (t < DD)
        ((float*)(sm + SM_KSX))[t] =
            ((const float*)(wsb + KS_BASE_BYTES))[(size_t)bid * DD + t];
    __syncthreads();

    // ---- q fragments (kept in regs through both phases) ----
    const bf16x8 qf0 = *(const bf16x8*)(sm + SM_Q + c*128 + SWZ8(c, 16*gq));
    const bf16x8 qf1 = *(const bf16x8*)(sm + SM_Q + c*128 + SWZ8(c, 64 + 16*gq));

    // ---- scores: S^T tiles, 8 r-tiles of 16 ----
    f32x4 sreg[8];
    #pragma unroll
    for (int tr = 0; tr < 8; ++tr) {
        const int r = 16*tr + c16;
        const bf16x8 ka0 = *(const bf16x8*)(sm + SM_K + r*128 + SWZ8(r, 16*gq));
        const bf16x8 ka1 = *(const bf16x8*)(sm + SM_K + r*128 + SWZ8(r, 64 + 16*gq));
        f32x4 a; a[0]=0.f; a[1]=0.f; a[2]=0.f; a[3]=0.f;
        a = __builtin_amdgcn_mfma_f32_16x16x32_bf16(ka0, qf0, a, 0, 0, 0);
        a = __builtin_amdgcn_mfma_f32_16x16x32_bf16(ka1, qf1, a, 0, 0, 0);
        sreg[tr] = a;
    }
    // causal mask (keep r <= c) + z intra partial
    float z = 0.f;
    #pragma unroll
    for (int tr = 0; tr < 8; ++tr)
        #pragma unroll
        for (int e = 0; e < 4; ++e) {
            const int rr = 16*tr + 4*gq + e;
            if (rr <= c) z += sreg[tr][e]; else sreg[tr][e] = 0.f;
        }
    // z inter partial from qf regs (lane holds d=8gq+[0,8) and 32+8gq+[0,8))
    {
        const float* ksxf = (const float*)(sm + SM_KSX);
        #pragma unroll
        for (int i = 0; i < 8; ++i) {
            z += bf2f((unsigned short)qf0[i]) * ksxf[8*gq + i];
            z += bf2f((unsigned short)qf1[i]) * ksxf[32 + 8*gq + i];
        }
    }
    z += __shfl_xor(z, 16);
    z += __shfl_xor(z, 32);
    __syncthreads();   // all Q/K LDS reads done before S overlays them

    // ---- write masked S bf16 as S[c][r] (256B rows, SWZ16) ----
    #pragma unroll
    for (int tr = 0; tr < 8; ++tr) {
        uint2 sp; sp.x = packbf(sreg[tr][0], sreg[tr][1]); sp.y = packbf(sreg[tr][2], sreg[tr][3]);
        *(uint2*)(sm + SM_S + c*256 + SWZ16(c, 32*tr + 8*gq)) = sp;
    }
    if (gq == 0) ((float*)(sm + SM_ZL))[c] = z;
    __syncthreads();

    // ---- PV intra (k=r, 4 steps) + inter (k=d, 2 steps) ----
    bf16x8 sf[4];
    #pragma unroll
    for (int ks = 0; ks < 4; ++ks)
        sf[ks] = *(const bf16x8*)(sm + SM_S + c*256 + SWZ16(c, 64*ks + 16*gq));
    f32x4 acc[4];
    #pragma unroll
    for (int tm = 0; tm < 4; ++tm) { acc[tm][0]=0.f; acc[tm][1]=0.f; acc[tm][2]=0.f; acc[tm][3]=0.f; }
    #pragma unroll
    for (int tm = 0; tm < 4; ++tm) {
        const int m = 16*tm + c16;
        #pragma unroll
        for (int ks = 0; ks < 4; ++ks) {
            const bf16x8 vf = *(const bf16x8*)(sm + SM_VT + m*256 + SWZ16(m, 64*ks + 16*gq));
            acc[tm] = __builtin_amdgcn_mfma_f32_16x16x32_bf16(sf[ks], vf, acc[tm], 0, 0, 0);
        }
        const bf16x8 st0 = *(const bf16x8*)(sm + SM_STX + m*128 + SWZ8(m, 16*gq));
        const bf16x8 st1 = *(const bf16x8*)(sm + SM_STX + m*128 + SWZ8(m, 64 + 16*gq));
        acc[tm] = __builtin_amdgcn_mfma_f32_16x16x32_bf16(qf0, st0, acc[tm], 0, 0, 0);
        acc[tm] = __builtin_amdgcn_mfma_f32_16x16x32_bf16(qf1, st1, acc[tm], 0, 0, 0);
    }

    // ---- epilogue ----
    float zinv[4];
    #pragma unroll
    for (int e = 0; e < 4; ++e) {
        const float zr = ((const float*)(sm + SM_ZL))[16*w + 4*gq + e];
        zinv[e] = 1.0f / (zr + 1e-6f);
    }
    #pragma unroll
    for (int tm = 0; tm < 4; ++tm)
        #pragma unroll
        for (int e = 0; e < 4; ++e) {
            const int cr = 16*w + 4*gq + e;
            const int m  = 16*tm + c16;
            out[((size_t)((n*LL + l0 + cr)*NH + h))*DD + m] = acc[tm][e] * zinv[e];
        }
}

extern "C" void kernel_launch(void* const* d_in, const int* in_sizes, int n_in,
                              void* d_out, int out_size, void* d_ws, size_t ws_size,
                              hipStream_t stream) {
    const float* q = (const float*)d_in[0];
    const float* k = (const float*)d_in[1];
    const float* v = (const float*)d_in[2];
    float* out = (float*)d_out;
    char* wsb  = (char*)d_ws;   // state bf16 6.29 MB + ksum f32 0.2 MB

    const int nblk = NB * NH * NG;   // 768
    la_chunk_sums<<<nblk, 256, 0, stream>>>(k, v, wsb);
    la_scan<<<NBH*3, 256, 0, stream>>>(wsb);
    la_output<<<nblk, 512, 0, stream>>>(q, k, v, wsb, out);
}